// Round 1
// baseline (941.445 us; speedup 1.0000x reference)
//
#include <hip/hip_runtime.h>
#include <math.h>

#define B_  2
#define S_  2048
#define E_  1024
#define H_  16
#define HD_ 64
#define N3_ 3072
#define M_  (B_*S_)   // 4096

// ---------------- kernel 0: per-key log-weight bias ----------------
// lw[b,k] = log(w + TINY), replaced by -9e15 (w==0) / +9e15 (w==1).
// Additive use later is exact: ulp(9e15) >> |dot/8|.
__global__ void logw_kernel(const float* __restrict__ w, float* __restrict__ lw) {
    int i = blockIdx.x * blockDim.x + threadIdx.x;
    if (i < B_ * S_) {
        float x = w[i];
        float v;
        if (x == 0.0f)       v = -9.0e15f;
        else if (x == 1.0f)  v =  9.0e15f;
        else                 v = logf(x + 1.17549435e-38f);
        lw[i] = v;
    }
}

// ---------------- kernel 1: QKV GEMM (fp32) + head-deinterleave scatter ----
// C[m,n] = x[m,:] @ W[:,n] + b[n];  n -> (h = n/192, which = (n%192)/64, d = n%64)
// dst[which][b,h,s,d], layout [B,H,S,64].
#define BM 128
#define BN 64
#define BK 16

__global__ __launch_bounds__(256) void qkv_gemm(
        const float* __restrict__ x, const float* __restrict__ Wq,
        const float* __restrict__ bq,
        float* __restrict__ qo, float* __restrict__ ko, float* __restrict__ vo) {
    __shared__ __align__(16) float As[BK][BM + 4];  // [k][m], stride 132 (528B, 16B-mult)
    __shared__ __align__(16) float Bs[BK][BN];      // [k][n]

    int tid = threadIdx.x;
    int tx = tid & 15, ty = tid >> 4;
    int n0 = blockIdx.x * BN;
    int m0 = blockIdx.y * BM;

    float acc[8][4];
#pragma unroll
    for (int i = 0; i < 8; i++)
#pragma unroll
        for (int j = 0; j < 4; j++) acc[i][j] = 0.0f;

    int ra = tid >> 2;          // 0..63
    int ca = (tid & 3) * 4;     // 0,4,8,12
    int rb = tid >> 4;          // 0..15
    int cb = (tid & 15) * 4;    // 0..60

    for (int k0 = 0; k0 < E_; k0 += BK) {
        float4 a0 = *(const float4*)&x[(size_t)(m0 + ra) * E_ + k0 + ca];
        float4 a1 = *(const float4*)&x[(size_t)(m0 + ra + 64) * E_ + k0 + ca];
        float4 b0 = *(const float4*)&Wq[(size_t)(k0 + rb) * N3_ + n0 + cb];
        As[ca + 0][ra] = a0.x; As[ca + 1][ra] = a0.y;
        As[ca + 2][ra] = a0.z; As[ca + 3][ra] = a0.w;
        As[ca + 0][ra + 64] = a1.x; As[ca + 1][ra + 64] = a1.y;
        As[ca + 2][ra + 64] = a1.z; As[ca + 3][ra + 64] = a1.w;
        *(float4*)&Bs[rb][cb] = b0;
        __syncthreads();
#pragma unroll
        for (int kk = 0; kk < BK; kk++) {
            float4 av0 = *(const float4*)&As[kk][ty * 8];
            float4 av1 = *(const float4*)&As[kk][ty * 8 + 4];
            float4 bv  = *(const float4*)&Bs[kk][tx * 4];
            float a[8] = {av0.x, av0.y, av0.z, av0.w, av1.x, av1.y, av1.z, av1.w};
            float b[4] = {bv.x, bv.y, bv.z, bv.w};
#pragma unroll
            for (int i = 0; i < 8; i++)
#pragma unroll
                for (int j = 0; j < 4; j++)
                    acc[i][j] = fmaf(a[i], b[j], acc[i][j]);
        }
        __syncthreads();
    }

    // epilogue: whole n-tile shares (h, which) since 192 = 3*64 and BN = 64
    int h = n0 / 192;
    int which = (n0 % 192) / 64;   // 0=q 1=k 2=v
    float* dst = (which == 0) ? qo : ((which == 1) ? ko : vo);
    float4 bias = *(const float4*)&bq[n0 + tx * 4];
#pragma unroll
    for (int i = 0; i < 8; i++) {
        int m = m0 + ty * 8 + i;
        int b = m >> 11;          // / 2048
        int s = m & 2047;
        int bh = b * H_ + h;
        float4 o;
        o.x = acc[i][0] + bias.x; o.y = acc[i][1] + bias.y;
        o.z = acc[i][2] + bias.z; o.w = acc[i][3] + bias.w;
        *(float4*)&dst[((size_t)(bh * S_ + s)) * HD_ + tx * 4] = o;
    }
}

// ---------------- kernel 2: flash attention (fp32, online softmax) --------
// Block: 256 thr, 64-query tile, iterate 32 key-tiles of 64.
// Q,K stored d-major in LDS (b128 reads in QK^T); V row-major (b128 in PV).
__global__ __launch_bounds__(256) void attn_kernel(
        const float* __restrict__ q, const float* __restrict__ k,
        const float* __restrict__ v, const float* __restrict__ lw,
        float* __restrict__ out) {
    __shared__ __align__(16) float QsT[HD_][68];   // [d][q-row], pre-scaled by 0.125
    __shared__ __align__(16) float KVs[HD_][68];   // K: [d][key]; later V: [key][d]
    __shared__ __align__(16) float Ss[64][68];     // P tile [q-row][key]
    __shared__ float m_sh[64], l_sh[64], lwt[64];

    int tid = threadIdx.x;
    int tx = tid & 15, ty = tid >> 4;
    int tx4 = tx * 4, ty4 = ty * 4;
    int qt = blockIdx.x;          // 0..31
    int bh = blockIdx.y;          // 0..31
    int b = bh >> 4, h = bh & 15;
    int q0 = qt * 64;
    const float* qbase = q + (size_t)bh * S_ * HD_;
    const float* kbase = k + (size_t)bh * S_ * HD_;
    const float* vbase = v + (size_t)bh * S_ * HD_;

    if (tid < 64) { m_sh[tid] = -INFINITY; l_sh[tid] = 0.0f; }

    {   // stage Q transposed + pre-scaled
        int r = tid >> 2;
        int c = (tid & 3) * 16;
#pragma unroll
        for (int ii = 0; ii < 4; ii++) {
            float4 t = *(const float4*)&qbase[(size_t)(q0 + r) * HD_ + c + ii * 4];
            QsT[c + ii * 4 + 0][r] = t.x * 0.125f;
            QsT[c + ii * 4 + 1][r] = t.y * 0.125f;
            QsT[c + ii * 4 + 2][r] = t.z * 0.125f;
            QsT[c + ii * 4 + 3][r] = t.w * 0.125f;
        }
    }

    float O[4][4];
#pragma unroll
    for (int i = 0; i < 4; i++)
#pragma unroll
        for (int j = 0; j < 4; j++) O[i][j] = 0.0f;

    __syncthreads();

    for (int kt = 0; kt < 32; kt++) {
        int k0 = kt * 64;
        if (tid < 64) lwt[tid] = lw[b * S_ + k0 + tid];
        {   // stage K transposed
            int r = tid >> 2;
            int c = (tid & 3) * 16;
#pragma unroll
            for (int ii = 0; ii < 4; ii++) {
                float4 t = *(const float4*)&kbase[(size_t)(k0 + r) * HD_ + c + ii * 4];
                KVs[c + ii * 4 + 0][r] = t.x;
                KVs[c + ii * 4 + 1][r] = t.y;
                KVs[c + ii * 4 + 2][r] = t.z;
                KVs[c + ii * 4 + 3][r] = t.w;
            }
        }
        __syncthreads();

        // ---- stage 1: S = (Q/8) K^T, 4x4 per thread ----
        float acc[4][4];
#pragma unroll
        for (int i = 0; i < 4; i++)
#pragma unroll
            for (int j = 0; j < 4; j++) acc[i][j] = 0.0f;
#pragma unroll 8
        for (int d = 0; d < HD_; d++) {
            float4 av = *(const float4*)&QsT[d][ty4];
            float4 bv = *(const float4*)&KVs[d][tx4];
            float a[4] = {av.x, av.y, av.z, av.w};
            float bb[4] = {bv.x, bv.y, bv.z, bv.w};
#pragma unroll
            for (int i = 0; i < 4; i++)
#pragma unroll
                for (int j = 0; j < 4; j++)
                    acc[i][j] = fmaf(a[i], bb[j], acc[i][j]);
        }

        // ---- bias + online softmax (16-lane row teams, wave-synchronous) ----
#pragma unroll
        for (int i = 0; i < 4; i++) {
            int r = ty4 + i;
            float s0 = acc[i][0] + lwt[tx4 + 0];
            float s1 = acc[i][1] + lwt[tx4 + 1];
            float s2 = acc[i][2] + lwt[tx4 + 2];
            float s3 = acc[i][3] + lwt[tx4 + 3];
            float rm = fmaxf(fmaxf(s0, s1), fmaxf(s2, s3));
            rm = fmaxf(rm, __shfl_xor(rm, 1));
            rm = fmaxf(rm, __shfl_xor(rm, 2));
            rm = fmaxf(rm, __shfl_xor(rm, 4));
            rm = fmaxf(rm, __shfl_xor(rm, 8));
            float mold = m_sh[r];
            float mnew = fmaxf(mold, rm);
            float e0 = __expf(s0 - mnew);
            float e1 = __expf(s1 - mnew);
            float e2 = __expf(s2 - mnew);
            float e3 = __expf(s3 - mnew);
            float rs = (e0 + e1) + (e2 + e3);
            rs += __shfl_xor(rs, 1);
            rs += __shfl_xor(rs, 2);
            rs += __shfl_xor(rs, 4);
            rs += __shfl_xor(rs, 8);
            float alpha = __expf(mold - mnew);
            O[i][0] *= alpha; O[i][1] *= alpha; O[i][2] *= alpha; O[i][3] *= alpha;
            if (tx == 0) { m_sh[r] = mnew; l_sh[r] = l_sh[r] * alpha + rs; }
            *(float4*)&Ss[r][tx4] = make_float4(e0, e1, e2, e3);
        }
        __syncthreads();   // everyone done with K tile (and lwt)

        {   // stage V row-major into same buffer
            int r = tid >> 2;
            int c = (tid & 3) * 16;
#pragma unroll
            for (int ii = 0; ii < 4; ii++) {
                float4 t = *(const float4*)&vbase[(size_t)(k0 + r) * HD_ + c + ii * 4];
                *(float4*)&KVs[r][c + ii * 4] = t;
            }
        }
        __syncthreads();

        // ---- stage 2: O += P V, 4x4 per thread ----
#pragma unroll 4
        for (int jj = 0; jj < 64; jj++) {
            float4 bv = *(const float4*)&KVs[jj][tx4];
            float a0 = Ss[ty4 + 0][jj];
            float a1 = Ss[ty4 + 1][jj];
            float a2 = Ss[ty4 + 2][jj];
            float a3 = Ss[ty4 + 3][jj];
            O[0][0] = fmaf(a0, bv.x, O[0][0]); O[0][1] = fmaf(a0, bv.y, O[0][1]);
            O[0][2] = fmaf(a0, bv.z, O[0][2]); O[0][3] = fmaf(a0, bv.w, O[0][3]);
            O[1][0] = fmaf(a1, bv.x, O[1][0]); O[1][1] = fmaf(a1, bv.y, O[1][1]);
            O[1][2] = fmaf(a1, bv.z, O[1][2]); O[1][3] = fmaf(a1, bv.w, O[1][3]);
            O[2][0] = fmaf(a2, bv.x, O[2][0]); O[2][1] = fmaf(a2, bv.y, O[2][1]);
            O[2][2] = fmaf(a2, bv.z, O[2][2]); O[2][3] = fmaf(a2, bv.w, O[2][3]);
            O[3][0] = fmaf(a3, bv.x, O[3][0]); O[3][1] = fmaf(a3, bv.y, O[3][1]);
            O[3][2] = fmaf(a3, bv.z, O[3][2]); O[3][3] = fmaf(a3, bv.w, O[3][3]);
        }
        __syncthreads();   // before next tile overwrites KVs / lwt
    }

    // ---- epilogue: normalize and store (out[b, s, h*64+d]) ----
#pragma unroll
    for (int i = 0; i < 4; i++) {
        int r = ty4 + i;
        float linv = 1.0f / l_sh[r];
        float4 o;
        o.x = O[i][0] * linv; o.y = O[i][1] * linv;
        o.z = O[i][2] * linv; o.w = O[i][3] * linv;
        *(float4*)&out[((size_t)(b * S_ + q0 + r)) * E_ + h * HD_ + tx4] = o;
    }
}

extern "C" void kernel_launch(void* const* d_in, const int* in_sizes, int n_in,
                              void* d_out, int out_size, void* d_ws, size_t ws_size,
                              hipStream_t stream) {
    const float* x  = (const float*)d_in[0];
    const float* w  = (const float*)d_in[1];
    const float* Wq = (const float*)d_in[2];
    const float* bq = (const float*)d_in[3];
    float* out = (float*)d_out;

    // workspace: q | k | v  (each B*H*S*64 fp32 = 16 MB) | logw (16 KB) => ~50.3 MB
    float* ws = (float*)d_ws;
    size_t per = (size_t)B_ * H_ * S_ * HD_;
    float* qb = ws;
    float* kb = ws + per;
    float* vb = ws + 2 * per;
    float* lwb = ws + 3 * per;

    logw_kernel<<<dim3((B_ * S_ + 255) / 256), dim3(256), 0, stream>>>(w, lwb);
    qkv_gemm<<<dim3(N3_ / BN, M_ / BM), dim3(256), 0, stream>>>(x, Wq, bq, qb, kb, vb);
    attn_kernel<<<dim3(S_ / 64, B_ * H_), dim3(256), 0, stream>>>(qb, kb, vb, lwb, out);
}

// Round 2
// 210.976 us; speedup vs baseline: 4.4623x; 4.4623x over previous
//
#include <hip/hip_runtime.h>
#include <math.h>

#define B_  2
#define S_  2048
#define E_  1024
#define H_  16
#define HD_ 64
#define N3_ 3072
#define M_  (B_*S_)   // 4096

typedef _Float16 h8 __attribute__((ext_vector_type(8)));
typedef _Float16 h4 __attribute__((ext_vector_type(4)));
typedef float    f4 __attribute__((ext_vector_type(4)));

// ---------------- kernel 0: per-key log-weight bias (fp32) ----------------
__global__ void logw_kernel(const float* __restrict__ w, float* __restrict__ lw) {
    int i = blockIdx.x * blockDim.x + threadIdx.x;
    if (i < B_ * S_) {
        float x = w[i];
        float v;
        if (x == 0.0f)       v = -9.0e15f;
        else if (x == 1.0f)  v =  9.0e15f;
        else                 v = logf(x + 1.17549435e-38f);
        lw[i] = v;
    }
}

// ---------------- kernel 0b: x fp32 -> f16 ----------------
__global__ void cvt_x_kernel(const float* __restrict__ x, _Float16* __restrict__ x16) {
    int i = (blockIdx.x * 256 + threadIdx.x) * 8;
    float4 u = *(const float4*)&x[i];
    float4 v = *(const float4*)&x[i + 4];
    h8 o;
    o[0] = (_Float16)u.x; o[1] = (_Float16)u.y; o[2] = (_Float16)u.z; o[3] = (_Float16)u.w;
    o[4] = (_Float16)v.x; o[5] = (_Float16)v.y; o[6] = (_Float16)v.z; o[7] = (_Float16)v.w;
    *(h8*)&x16[i] = o;
}

// ---------------- kernel 0c: W [K][N] fp32 -> Wt [N][K] f16 ----------------
__global__ __launch_bounds__(256) void transpose_w_kernel(
        const float* __restrict__ W, _Float16* __restrict__ Wt) {
    __shared__ float T[64][65];   // [n][k]
    int k0 = blockIdx.x * 64, n0 = blockIdx.y * 64;
    int tid = threadIdx.x;
    int r = tid >> 4, c4 = (tid & 15) * 4;
#pragma unroll
    for (int i = 0; i < 4; i++) {
        int row = r + i * 16;   // k-row
        float4 u = *(const float4*)&W[(size_t)(k0 + row) * N3_ + n0 + c4];
        T[c4 + 0][row] = u.x; T[c4 + 1][row] = u.y;
        T[c4 + 2][row] = u.z; T[c4 + 3][row] = u.w;
    }
    __syncthreads();
#pragma unroll
    for (int i = 0; i < 4; i++) {
        int rn = r + i * 16;    // n-row
        h4 p;
        p[0] = (_Float16)T[rn][c4 + 0]; p[1] = (_Float16)T[rn][c4 + 1];
        p[2] = (_Float16)T[rn][c4 + 2]; p[3] = (_Float16)T[rn][c4 + 3];
        *(h4*)&Wt[(size_t)(n0 + rn) * E_ + k0 + c4] = p;
    }
}

// ---------------- kernel 1: QKV GEMM, f16 MFMA ----------------
// BM=256 BN=64 BK=64; block pure q/k/v (n-range 64-wide, 64-aligned).
// Q/K blocks: mfma(w,a) -> D[d][s] -> b64 stores into [s][d] layout.
// V  blocks: mfma(a,w) -> D[s][d] -> b64 stores into Vt [d][s] layout.
__global__ __launch_bounds__(256) void qkv_gemm_f16(
        const _Float16* __restrict__ x16, const _Float16* __restrict__ wt,
        const float* __restrict__ bq,
        _Float16* __restrict__ qws, _Float16* __restrict__ kws,
        _Float16* __restrict__ vtws) {
    __shared__ _Float16 As[256 * 72];   // 36 KB, stride 72 f16 (144B)
    __shared__ _Float16 Ws[64 * 72];    //  9 KB

    int tid = threadIdx.x;
    int wid = tid >> 6;
    int ln = tid & 15;
    int qd = (tid & 63) >> 4;
    int n0 = blockIdx.x * 64;
    int m0 = blockIdx.y * 256;
    int h = n0 / 192;
    int which = (n0 % 192) / 64;
    bool isV = (which == 2);

    f4 acc[4][4];
#pragma unroll
    for (int i = 0; i < 4; i++)
#pragma unroll
        for (int j = 0; j < 4; j++) acc[i][j] = (f4)0.0f;

    int sr = tid >> 3;          // 0..31
    int sc = (tid & 7) * 8;     // 0..56

    for (int k0 = 0; k0 < E_; k0 += 64) {
#pragma unroll
        for (int i = 0; i < 8; i++) {
            int row = sr + 32 * i;
            *(h8*)&As[row * 72 + sc] = *(const h8*)&x16[(size_t)(m0 + row) * E_ + k0 + sc];
        }
#pragma unroll
        for (int i = 0; i < 2; i++) {
            int row = sr + 32 * i;
            *(h8*)&Ws[row * 72 + sc] = *(const h8*)&wt[(size_t)(n0 + row) * E_ + k0 + sc];
        }
        __syncthreads();
#pragma unroll
        for (int ks = 0; ks < 2; ks++) {
            h8 a[4], b[4];
#pragma unroll
            for (int mt = 0; mt < 4; mt++)
                a[mt] = *(const h8*)&As[(wid * 64 + mt * 16 + ln) * 72 + ks * 32 + qd * 8];
#pragma unroll
            for (int nt = 0; nt < 4; nt++)
                b[nt] = *(const h8*)&Ws[(nt * 16 + ln) * 72 + ks * 32 + qd * 8];
            if (isV) {
#pragma unroll
                for (int i = 0; i < 4; i++)
#pragma unroll
                    for (int j = 0; j < 4; j++)
                        acc[i][j] = __builtin_amdgcn_mfma_f32_16x16x32_f16(a[i], b[j], acc[i][j], 0, 0, 0);
            } else {
#pragma unroll
                for (int i = 0; i < 4; i++)
#pragma unroll
                    for (int j = 0; j < 4; j++)
                        acc[i][j] = __builtin_amdgcn_mfma_f32_16x16x32_f16(b[i], a[j], acc[i][j], 0, 0, 0);
            }
        }
        __syncthreads();
    }

    int b = m0 >> 11;
    int bh = b * H_ + h;
    int sbase = (m0 & 2047) + wid * 64;

    if (isV) {
        // acc[mt][nt]: rows = s (qd*4+reg), cols = d (ln)
#pragma unroll
        for (int mt = 0; mt < 4; mt++) {
#pragma unroll
            for (int nt = 0; nt < 4; nt++) {
                int d = nt * 16 + ln;
                float bias = bq[n0 + nt * 16 + ln];
                f4 v = acc[mt][nt];
                h4 p;
                p[0] = (_Float16)(v[0] + bias); p[1] = (_Float16)(v[1] + bias);
                p[2] = (_Float16)(v[2] + bias); p[3] = (_Float16)(v[3] + bias);
                int s0 = sbase + mt * 16 + qd * 4;
                *(h4*)&vtws[((size_t)(bh * HD_ + d)) * S_ + s0] = p;
            }
        }
    } else {
        _Float16* dst = (which == 0) ? qws : kws;
        float scale = (which == 0) ? 0.125f : 1.0f;
        // acc[nt][mt]: rows = d (qd*4+reg), cols = s (ln)
#pragma unroll
        for (int nt = 0; nt < 4; nt++) {
            f4 bias4 = *(const f4*)&bq[n0 + nt * 16 + qd * 4];
#pragma unroll
            for (int mt = 0; mt < 4; mt++) {
                int s = sbase + mt * 16 + ln;
                f4 v = (acc[nt][mt] + bias4) * scale;
                h4 p;
                p[0] = (_Float16)v[0]; p[1] = (_Float16)v[1];
                p[2] = (_Float16)v[2]; p[3] = (_Float16)v[3];
                *(h4*)&dst[(((size_t)bh * S_ + s)) * HD_ + nt * 16 + qd * 4] = p;
            }
        }
    }
}

// ---------------- kernel 2: flash attention, f16 MFMA ----------------
// Block: 256 thr (4 waves), Q-tile 128 (32 q-rows/wave), K-tile 64/iter.
// S^T = K*Q^T via mfma(k,q): C rows = k -> b64 P^T-pack -> P[q][k] LDS,
// wave-private; PV reads P as A-frags (b128) and Vt as B-frags (b128).
__global__ __launch_bounds__(256) void attn_kernel(
        const _Float16* __restrict__ q, const _Float16* __restrict__ k,
        const _Float16* __restrict__ vt, const float* __restrict__ lw,
        float* __restrict__ out) {
    __shared__ _Float16 Ks[64 * 72];     // [k-row][d], 9216 B
    __shared__ _Float16 Vts[64 * 72];    // [d][k-local]
    __shared__ _Float16 Ps[128 * 72];    // [q-local][k-local], wave-private rows
    __shared__ float lws[64];
    __shared__ float abuf[4][32];

    int tid = threadIdx.x;
    int wid = tid >> 6;
    int ln = tid & 15;
    int qd = (tid & 63) >> 4;
    int q0 = blockIdx.x * 128;
    int bh = blockIdx.y;
    int b = bh >> 4, h = bh & 15;

    const _Float16* qbase = q + (size_t)bh * S_ * HD_;
    const _Float16* kbase = k + (size_t)bh * S_ * HD_;
    const _Float16* vbase = vt + (size_t)bh * HD_ * S_;

    // Q fragments resident in registers (q pre-scaled by 1/8 at GEMM)
    h8 qf[2][2];
#pragma unroll
    for (int qt = 0; qt < 2; qt++)
#pragma unroll
        for (int ds = 0; ds < 2; ds++)
            qf[qt][ds] = *(const h8*)&qbase[(size_t)(q0 + wid * 32 + qt * 16 + ln) * HD_ + ds * 32 + qd * 8];

    f4 o[2][4];
#pragma unroll
    for (int i = 0; i < 2; i++)
#pragma unroll
        for (int j = 0; j < 4; j++) o[i][j] = (f4)0.0f;
    float m_r[2] = {-INFINITY, -INFINITY};
    float l_r[2] = {0.0f, 0.0f};

    int sr = tid >> 3;          // 0..31
    int sc = (tid & 7) * 8;     // 0..56

    for (int kt = 0; kt < 32; kt++) {
        int k0 = kt * 64;
        // ---- stage K, Vt, lw ----
#pragma unroll
        for (int i = 0; i < 2; i++) {
            int row = sr + 32 * i;
            *(h8*)&Ks[row * 72 + sc]  = *(const h8*)&kbase[(size_t)(k0 + row) * HD_ + sc];
            *(h8*)&Vts[row * 72 + sc] = *(const h8*)&vbase[(size_t)row * S_ + k0 + sc];
        }
        if (tid < 64) lws[tid] = lw[b * S_ + k0 + tid];
        __syncthreads();

        // ---- S^T = K * Q^T : st[kt16][qt], rows=k, cols=q ----
        f4 st[4][2];
#pragma unroll
        for (int i = 0; i < 4; i++)
#pragma unroll
            for (int j = 0; j < 2; j++) st[i][j] = (f4)0.0f;
#pragma unroll
        for (int ds = 0; ds < 2; ds++) {
            h8 kf[4];
#pragma unroll
            for (int i = 0; i < 4; i++)
                kf[i] = *(const h8*)&Ks[(i * 16 + ln) * 72 + ds * 32 + qd * 8];
#pragma unroll
            for (int i = 0; i < 4; i++)
#pragma unroll
                for (int qt = 0; qt < 2; qt++)
                    st[i][qt] = __builtin_amdgcn_mfma_f32_16x16x32_f16(kf[i], qf[qt][ds], st[i][qt], 0, 0, 0);
        }

        // ---- bias + online softmax (per lane: q = qt*16+ln) ----
        f4 lwv[4];
#pragma unroll
        for (int i = 0; i < 4; i++)
            lwv[i] = *(const f4*)&lws[i * 16 + qd * 4];
#pragma unroll
        for (int qt = 0; qt < 2; qt++) {
            float sv[16];
            float rm = -INFINITY;
#pragma unroll
            for (int i = 0; i < 4; i++)
#pragma unroll
                for (int r = 0; r < 4; r++) {
                    float v = st[i][qt][r] + lwv[i][r];
                    sv[i * 4 + r] = v;
                    rm = fmaxf(rm, v);
                }
            rm = fmaxf(rm, __shfl_xor(rm, 16));
            rm = fmaxf(rm, __shfl_xor(rm, 32));
            float mnew = fmaxf(m_r[qt], rm);
            float rs = 0.0f;
#pragma unroll
            for (int i = 0; i < 16; i++) {
                float e = __expf(sv[i] - mnew);
                sv[i] = e;
                rs += e;
            }
            rs += __shfl_xor(rs, 16);
            rs += __shfl_xor(rs, 32);
            float alpha = __expf(m_r[qt] - mnew);
            m_r[qt] = mnew;
            l_r[qt] = l_r[qt] * alpha + rs;
            if (qd == 0) abuf[wid][qt * 16 + ln] = alpha;
#pragma unroll
            for (int i = 0; i < 4; i++) {
                h4 p;
                p[0] = (_Float16)sv[i * 4 + 0]; p[1] = (_Float16)sv[i * 4 + 1];
                p[2] = (_Float16)sv[i * 4 + 2]; p[3] = (_Float16)sv[i * 4 + 3];
                *(h4*)&Ps[(wid * 32 + qt * 16 + ln) * 72 + i * 16 + qd * 4] = p;
            }
        }
        asm volatile("s_waitcnt lgkmcnt(0)" ::: "memory");

        // ---- rescale O by alpha (rows of O are q = mt*16 + qd*4 + reg) ----
#pragma unroll
        for (int mt = 0; mt < 2; mt++) {
            f4 af = *(const f4*)&abuf[wid][mt * 16 + qd * 4];
#pragma unroll
            for (int nt = 0; nt < 4; nt++) o[mt][nt] *= af;
        }

        // ---- O += P * V ----
#pragma unroll
        for (int ks = 0; ks < 2; ks++) {
            h8 pf[2], vf[4];
#pragma unroll
            for (int mt = 0; mt < 2; mt++)
                pf[mt] = *(const h8*)&Ps[(wid * 32 + mt * 16 + ln) * 72 + ks * 32 + qd * 8];
#pragma unroll
            for (int nt = 0; nt < 4; nt++)
                vf[nt] = *(const h8*)&Vts[(nt * 16 + ln) * 72 + ks * 32 + qd * 8];
#pragma unroll
            for (int mt = 0; mt < 2; mt++)
#pragma unroll
                for (int nt = 0; nt < 4; nt++)
                    o[mt][nt] = __builtin_amdgcn_mfma_f32_16x16x32_f16(pf[mt], vf[nt], o[mt][nt], 0, 0, 0);
        }
        __syncthreads();
    }

    // ---- epilogue: 1/l redistribution + store ----
    if (qd == 0) {
        abuf[wid][ln] = l_r[0];
        abuf[wid][16 + ln] = l_r[1];
    }
    asm volatile("s_waitcnt lgkmcnt(0)" ::: "memory");
#pragma unroll
    for (int mt = 0; mt < 2; mt++) {
        f4 lf = *(const f4*)&abuf[wid][mt * 16 + qd * 4];
        f4 linv;
        linv[0] = 1.0f / lf[0]; linv[1] = 1.0f / lf[1];
        linv[2] = 1.0f / lf[2]; linv[3] = 1.0f / lf[3];
#pragma unroll
        for (int nt = 0; nt < 4; nt++) {
#pragma unroll
            for (int r = 0; r < 4; r++) {
                int s = q0 + wid * 32 + mt * 16 + qd * 4 + r;
                out[((size_t)(b * S_ + s)) * E_ + h * HD_ + nt * 16 + ln] = o[mt][nt][r] * linv[r];
            }
        }
    }
}

extern "C" void kernel_launch(void* const* d_in, const int* in_sizes, int n_in,
                              void* d_out, int out_size, void* d_ws, size_t ws_size,
                              hipStream_t stream) {
    const float* x  = (const float*)d_in[0];
    const float* w  = (const float*)d_in[1];
    const float* Wq = (const float*)d_in[2];
    const float* bq = (const float*)d_in[3];
    float* out = (float*)d_out;

    // ws layout (f16 buffers), all 256B-aligned sizes:
    // x16: 4M f16 (8 MB) | wt: 3M f16 (6 MB) | q,k: 4M f16 each (8 MB) |
    // vt: 4M f16 (8 MB) | lw: 4096 f32 (16 KB)   => ~38.4 MB
    char* p = (char*)d_ws;
    _Float16* x16 = (_Float16*)p;              p += (size_t)M_ * E_ * 2;
    _Float16* wt  = (_Float16*)p;              p += (size_t)E_ * N3_ * 2;
    _Float16* qb  = (_Float16*)p;              p += (size_t)M_ * E_ * 2;
    _Float16* kb  = (_Float16*)p;              p += (size_t)M_ * E_ * 2;
    _Float16* vtb = (_Float16*)p;              p += (size_t)M_ * E_ * 2;
    float* lwb    = (float*)p;

    logw_kernel<<<dim3((B_ * S_ + 255) / 256), dim3(256), 0, stream>>>(w, lwb);
    cvt_x_kernel<<<dim3(M_ * E_ / 2048), dim3(256), 0, stream>>>(x, x16);
    transpose_w_kernel<<<dim3(E_ / 64, N3_ / 64), dim3(256), 0, stream>>>(Wq, wt);
    qkv_gemm_f16<<<dim3(N3_ / 64, M_ / 256), dim3(256), 0, stream>>>(x16, wt, bq, qb, kb, vtb);
    attn_kernel<<<dim3(S_ / 128, B_ * H_), dim3(256), 0, stream>>>(qb, kb, vtb, lwb, out);
}

// Round 4
// 190.781 us; speedup vs baseline: 4.9347x; 1.1059x over previous
//
#include <hip/hip_runtime.h>
#include <math.h>

#define B_  2
#define S_  2048
#define E_  1024
#define H_  16
#define HD_ 64
#define N3_ 3072
#define M_  (B_*S_)   // 4096

typedef _Float16 h8 __attribute__((ext_vector_type(8)));
typedef _Float16 h4 __attribute__((ext_vector_type(4)));
typedef float    f4 __attribute__((ext_vector_type(4)));

typedef __attribute__((address_space(3))) unsigned int       lds_u32;
typedef const __attribute__((address_space(1))) unsigned int glob_u32;

// async global->LDS, 16B per lane; LDS dest = wave-uniform base + lane*16.
__device__ __forceinline__ void gld16(const void* g, void* l) {
    __builtin_amdgcn_global_load_lds((glob_u32*)g, (lds_u32*)l, 16, 0, 0);
}

// 2^x via v_exp_f32 (base-2 hardware exp; avoids glibc __exp2f macro clash)
__device__ __forceinline__ float exp2_hw(float x) {
    return __builtin_amdgcn_exp2f(x);
}

#define QSCALE 0.18033688011112042f   // log2(e)/8

// ---------------- kernel 0: per-key bias, base-2 ----------------
// lw = log2(w+TINY); +-9e15 sentinels keep exact reference semantics
// (all-equal-max sharing for w==1, zeroing for w==0).
__global__ void logw_kernel(const float* __restrict__ w, float* __restrict__ lw) {
    int i = blockIdx.x * blockDim.x + threadIdx.x;
    if (i < B_ * S_) {
        float x = w[i];
        float v;
        if (x == 0.0f)       v = -9.0e15f;
        else if (x == 1.0f)  v =  9.0e15f;
        else                 v = log2f(x + 1.17549435e-38f);
        lw[i] = v;
    }
}

// ---------------- kernel 0b: x fp32 -> f16 ----------------
__global__ void cvt_x_kernel(const float* __restrict__ x, _Float16* __restrict__ x16) {
    int i = (blockIdx.x * 256 + threadIdx.x) * 8;
    float4 u = *(const float4*)&x[i];
    float4 v = *(const float4*)&x[i + 4];
    h8 o;
    o[0] = (_Float16)u.x; o[1] = (_Float16)u.y; o[2] = (_Float16)u.z; o[3] = (_Float16)u.w;
    o[4] = (_Float16)v.x; o[5] = (_Float16)v.y; o[6] = (_Float16)v.z; o[7] = (_Float16)v.w;
    *(h8*)&x16[i] = o;
}

// ---------------- kernel 0c: W [K][N] fp32 -> Wt [N][K] f16 ----------------
__global__ __launch_bounds__(256) void transpose_w_kernel(
        const float* __restrict__ W, _Float16* __restrict__ Wt) {
    __shared__ float T[64][65];
    int k0 = blockIdx.x * 64, n0 = blockIdx.y * 64;
    int tid = threadIdx.x;
    int r = tid >> 4, c4 = (tid & 15) * 4;
#pragma unroll
    for (int i = 0; i < 4; i++) {
        int row = r + i * 16;
        float4 u = *(const float4*)&W[(size_t)(k0 + row) * N3_ + n0 + c4];
        T[c4 + 0][row] = u.x; T[c4 + 1][row] = u.y;
        T[c4 + 2][row] = u.z; T[c4 + 3][row] = u.w;
    }
    __syncthreads();
#pragma unroll
    for (int i = 0; i < 4; i++) {
        int rn = r + i * 16;
        h4 p;
        p[0] = (_Float16)T[rn][c4 + 0]; p[1] = (_Float16)T[rn][c4 + 1];
        p[2] = (_Float16)T[rn][c4 + 2]; p[3] = (_Float16)T[rn][c4 + 3];
        *(h4*)&Wt[(size_t)(n0 + rn) * E_ + k0 + c4] = p;
    }
}

// ---------------- kernel 1: QKV GEMM, f16 MFMA, async staging ----------------
// BM=256 BN=64 BK=64. LDS tiles stride-64 (no pad), global-side XOR swizzle:
// physical chunk p of row r holds global chunk p^(r&7); frag reads use c^(ln&7)
// -> 2-way banks (free). Bias folded into acc init.
__global__ __launch_bounds__(256) void qkv_gemm_f16(
        const _Float16* __restrict__ x16, const _Float16* __restrict__ wt,
        const float* __restrict__ bq,
        _Float16* __restrict__ qws, _Float16* __restrict__ kws,
        _Float16* __restrict__ vtws) {
    __shared__ __align__(16) _Float16 As[256 * 64];   // 32 KB
    __shared__ __align__(16) _Float16 Ws[64 * 64];    //  8 KB

    int tid = threadIdx.x;
    int wid = tid >> 6, lane = tid & 63;
    int ln = tid & 15, qd = lane >> 4;
    int n0 = blockIdx.x * 64;
    int m0 = blockIdx.y * 256;
    int h = n0 / 192;
    int which = (n0 % 192) / 64;
    bool isV = (which == 2);

    int srow = lane >> 3;              // 0..7
    int schunk = (lane & 7) ^ srow;    // swizzled global chunk

    f4 acc[4][4];
    if (isV) {
#pragma unroll
        for (int nt = 0; nt < 4; nt++) {
            float bv = bq[n0 + nt * 16 + ln];
            f4 b4; b4[0] = bv; b4[1] = bv; b4[2] = bv; b4[3] = bv;
#pragma unroll
            for (int mt = 0; mt < 4; mt++) acc[mt][nt] = b4;
        }
    } else {
#pragma unroll
        for (int nt = 0; nt < 4; nt++) {
            f4 b4 = *(const f4*)&bq[n0 + nt * 16 + qd * 4];
#pragma unroll
            for (int mt = 0; mt < 4; mt++) acc[nt][mt] = b4;
        }
    }

    const _Float16* agp = &x16[(size_t)(m0 + wid * 64 + srow) * E_ + schunk * 8];
    const _Float16* wgp = &wt[(size_t)(n0 + wid * 16 + srow) * E_ + schunk * 8];
    int sw = ln & 7;

    for (int k0 = 0; k0 < E_; k0 += 64) {
#pragma unroll
        for (int j = 0; j < 8; j++)
            gld16(agp + (size_t)j * 8 * E_ + k0, &As[(wid * 64 + j * 8) * 64]);
#pragma unroll
        for (int j = 0; j < 2; j++)
            gld16(wgp + (size_t)j * 8 * E_ + k0, &Ws[(wid * 16 + j * 8) * 64]);
        __syncthreads();
#pragma unroll
        for (int ks = 0; ks < 2; ks++) {
            int ch = ((ks * 4 + qd) ^ sw) * 8;
            h8 a[4], b[4];
#pragma unroll
            for (int mt = 0; mt < 4; mt++)
                a[mt] = *(const h8*)&As[(wid * 64 + mt * 16 + ln) * 64 + ch];
#pragma unroll
            for (int nt = 0; nt < 4; nt++)
                b[nt] = *(const h8*)&Ws[(nt * 16 + ln) * 64 + ch];
            if (isV) {
#pragma unroll
                for (int i = 0; i < 4; i++)
#pragma unroll
                    for (int j = 0; j < 4; j++)
                        acc[i][j] = __builtin_amdgcn_mfma_f32_16x16x32_f16(a[i], b[j], acc[i][j], 0, 0, 0);
            } else {
#pragma unroll
                for (int i = 0; i < 4; i++)
#pragma unroll
                    for (int j = 0; j < 4; j++)
                        acc[i][j] = __builtin_amdgcn_mfma_f32_16x16x32_f16(b[i], a[j], acc[i][j], 0, 0, 0);
            }
        }
        __syncthreads();
    }

    int b = m0 >> 11;
    int bh = b * H_ + h;
    int sbase = (m0 & 2047) + wid * 64;

    if (isV) {
        // acc[mt][nt]: rows = s (qd*4+reg), cols = d (ln); store Vt[d][s]
#pragma unroll
        for (int mt = 0; mt < 4; mt++)
#pragma unroll
            for (int nt = 0; nt < 4; nt++) {
                f4 v = acc[mt][nt];
                h4 p;
                p[0] = (_Float16)v[0]; p[1] = (_Float16)v[1];
                p[2] = (_Float16)v[2]; p[3] = (_Float16)v[3];
                *(h4*)&vtws[((size_t)(bh * HD_ + nt * 16 + ln)) * S_ + sbase + mt * 16 + qd * 4] = p;
            }
    } else {
        _Float16* dst = (which == 0) ? qws : kws;
        float scale = (which == 0) ? QSCALE : 1.0f;
        // acc[nt][mt]: rows = d (qd*4+reg), cols = s (ln); store [s][d]
#pragma unroll
        for (int nt = 0; nt < 4; nt++)
#pragma unroll
            for (int mt = 0; mt < 4; mt++) {
                f4 v = acc[nt][mt] * scale;
                h4 p;
                p[0] = (_Float16)v[0]; p[1] = (_Float16)v[1];
                p[2] = (_Float16)v[2]; p[3] = (_Float16)v[3];
                *(h4*)&dst[(((size_t)bh * S_ + sbase + mt * 16 + ln)) * HD_ + nt * 16 + qd * 4] = p;
            }
    }
}

// ---------------- kernel 2: flash attention, f16 MFMA ----------------
// Q-tile 64 (16 q-rows/wave), K-tile 64, grid 1024 1-D, XCD-pinned bh.
// S^T = K*Q^T with bias in C-init; base-2 online softmax (v_exp_f32);
// P via wave-private LDS transpose; K/Vt async-staged with XOR swizzle.
__global__ __launch_bounds__(256, 4) void attn_kernel(
        const _Float16* __restrict__ q, const _Float16* __restrict__ k,
        const _Float16* __restrict__ vt, const float* __restrict__ lw,
        float* __restrict__ out) {
    __shared__ __align__(16) _Float16 Ks[64 * 64];    // 8 KB, swizzled
    __shared__ __align__(16) _Float16 Vts[64 * 64];   // 8 KB, swizzled
    __shared__ __align__(16) _Float16 Ps[64 * 72];    // 9 KB, padded
    __shared__ float lws[64];
    __shared__ float abuf[4][16];

    int tid = threadIdx.x;
    int wid = tid >> 6, lane = tid & 63;
    int ln = tid & 15, qd = lane >> 4;
    int L = blockIdx.x;
    int sl = L >> 3;
    int bh = (L & 7) + 8 * (sl >> 5);   // all 32 q-tiles of a bh on one XCD
    int q0 = (sl & 31) * 64;
    int b = bh >> 4, h = bh & 15;

    const _Float16* qbase = q + (size_t)bh * S_ * HD_;
    const _Float16* kbase = k + (size_t)bh * S_ * HD_;
    const _Float16* vbase = vt + (size_t)bh * HD_ * S_;

    int srow = lane >> 3;
    int schunk = (lane & 7) ^ srow;
    int sw = ln & 7;

    // Q fragments resident (pre-scaled by log2(e)/8 at GEMM)
    h8 qf[2];
#pragma unroll
    for (int ds = 0; ds < 2; ds++)
        qf[ds] = *(const h8*)&qbase[(size_t)(q0 + wid * 16 + ln) * HD_ + ds * 32 + qd * 8];

    f4 o[4];
#pragma unroll
    for (int j = 0; j < 4; j++) o[j] = (f4)0.0f;
    float m_r = -INFINITY, l_r = 0.0f;

    const _Float16* kgp = &kbase[(size_t)(wid * 16 + srow) * HD_ + schunk * 8];
    const _Float16* vgp = &vbase[(size_t)(wid * 16 + srow) * S_ + schunk * 8];

    for (int kt = 0; kt < 32; kt++) {
        int k0 = kt * 64;
#pragma unroll
        for (int j = 0; j < 2; j++) {
            gld16(kgp + (size_t)(k0 + j * 8) * HD_, &Ks[(wid * 16 + j * 8) * 64]);
            gld16(vgp + (size_t)j * 8 * S_ + k0, &Vts[(wid * 16 + j * 8) * 64]);
        }
        if (tid < 64) lws[tid] = lw[b * S_ + k0 + tid];
        __syncthreads();

        // ---- S^T = K*Q^T + bias(C-init); rows=k (qd*4+r), cols=q (ln) ----
        f4 st[4];
#pragma unroll
        for (int i = 0; i < 4; i++) st[i] = *(const f4*)&lws[i * 16 + qd * 4];
#pragma unroll
        for (int ds = 0; ds < 2; ds++) {
            int ch = ((ds * 4 + qd) ^ sw) * 8;
            h8 kf[4];
#pragma unroll
            for (int i = 0; i < 4; i++)
                kf[i] = *(const h8*)&Ks[(i * 16 + ln) * 64 + ch];
#pragma unroll
            for (int i = 0; i < 4; i++)
                st[i] = __builtin_amdgcn_mfma_f32_16x16x32_f16(kf[i], qf[ds], st[i], 0, 0, 0);
        }

        // ---- base-2 online softmax; lane owns q = wid*16+ln, 16 k's ----
        float rm = -INFINITY;
#pragma unroll
        for (int i = 0; i < 4; i++)
#pragma unroll
            for (int r = 0; r < 4; r++) rm = fmaxf(rm, st[i][r]);
        rm = fmaxf(rm, __shfl_xor(rm, 16));
        rm = fmaxf(rm, __shfl_xor(rm, 32));
        float mnew = fmaxf(m_r, rm);
        float rs = 0.0f;
#pragma unroll
        for (int i = 0; i < 4; i++)
#pragma unroll
            for (int r = 0; r < 4; r++) {
                float e = exp2_hw(st[i][r] - mnew);
                st[i][r] = e;
                rs += e;
            }
        rs += __shfl_xor(rs, 16);
        rs += __shfl_xor(rs, 32);
        float alpha = exp2_hw(m_r - mnew);
        m_r = mnew;
        l_r = l_r * alpha + rs;
        if (qd == 0) abuf[wid][ln] = alpha;
#pragma unroll
        for (int i = 0; i < 4; i++) {
            h4 p;
            p[0] = (_Float16)st[i][0]; p[1] = (_Float16)st[i][1];
            p[2] = (_Float16)st[i][2]; p[3] = (_Float16)st[i][3];
            *(h4*)&Ps[(wid * 16 + ln) * 72 + i * 16 + qd * 4] = p;
        }
        asm volatile("s_waitcnt lgkmcnt(0)" ::: "memory");

        // ---- rescale O (rows q = qd*4+r) ----
        f4 af = *(const f4*)&abuf[wid][qd * 4];
#pragma unroll
        for (int nt = 0; nt < 4; nt++) o[nt] *= af;

        // ---- O += P*V ----
#pragma unroll
        for (int ks = 0; ks < 2; ks++) {
            int ch = ((ks * 4 + qd) ^ sw) * 8;
            h8 pf = *(const h8*)&Ps[(wid * 16 + ln) * 72 + ks * 32 + qd * 8];
            h8 vf[4];
#pragma unroll
            for (int nt = 0; nt < 4; nt++)
                vf[nt] = *(const h8*)&Vts[(nt * 16 + ln) * 64 + ch];
#pragma unroll
            for (int nt = 0; nt < 4; nt++)
                o[nt] = __builtin_amdgcn_mfma_f32_16x16x32_f16(pf, vf[nt], o[nt], 0, 0, 0);
        }
        __syncthreads();
    }

    // ---- epilogue ----
    if (qd == 0) abuf[wid][ln] = l_r;
    asm volatile("s_waitcnt lgkmcnt(0)" ::: "memory");
    f4 lf = *(const f4*)&abuf[wid][qd * 4];
    f4 linv;
    linv[0] = 1.0f / lf[0]; linv[1] = 1.0f / lf[1];
    linv[2] = 1.0f / lf[2]; linv[3] = 1.0f / lf[3];
    float* obase = &out[((size_t)(b * S_ + q0 + wid * 16 + qd * 4)) * E_ + h * HD_];
#pragma unroll
    for (int nt = 0; nt < 4; nt++)
#pragma unroll
        for (int r = 0; r < 4; r++)
            obase[(size_t)r * E_ + nt * 16 + ln] = o[nt][r] * linv[r];
}

extern "C" void kernel_launch(void* const* d_in, const int* in_sizes, int n_in,
                              void* d_out, int out_size, void* d_ws, size_t ws_size,
                              hipStream_t stream) {
    const float* x  = (const float*)d_in[0];
    const float* w  = (const float*)d_in[1];
    const float* Wq = (const float*)d_in[2];
    const float* bq = (const float*)d_in[3];
    float* out = (float*)d_out;

    char* p = (char*)d_ws;
    _Float16* x16 = (_Float16*)p;              p += (size_t)M_ * E_ * 2;
    _Float16* wt  = (_Float16*)p;              p += (size_t)E_ * N3_ * 2;
    _Float16* qb  = (_Float16*)p;              p += (size_t)M_ * E_ * 2;
    _Float16* kb  = (_Float16*)p;              p += (size_t)M_ * E_ * 2;
    _Float16* vtb = (_Float16*)p;              p += (size_t)M_ * E_ * 2;
    float* lwb    = (float*)p;

    logw_kernel<<<dim3((B_ * S_ + 255) / 256), dim3(256), 0, stream>>>(w, lwb);
    cvt_x_kernel<<<dim3(M_ * E_ / 2048), dim3(256), 0, stream>>>(x, x16);
    transpose_w_kernel<<<dim3(E_ / 64, N3_ / 64), dim3(256), 0, stream>>>(Wq, wt);
    qkv_gemm_f16<<<dim3(N3_ / 64, M_ / 256), dim3(256), 0, stream>>>(x16, wt, bq, qb, kb, vtb);
    attn_kernel<<<dim3(S_ / 64 * B_ * H_), dim3(256), 0, stream>>>(qb, kb, vtb, lwb, out);
}

// Round 5
// 186.440 us; speedup vs baseline: 5.0496x; 1.0233x over previous
//
#include <hip/hip_runtime.h>
#include <math.h>

#define B_  2
#define S_  2048
#define E_  1024
#define H_  16
#define HD_ 64
#define N3_ 3072
#define M_  (B_*S_)   // 4096

typedef _Float16 h8  __attribute__((ext_vector_type(8)));
typedef _Float16 h4  __attribute__((ext_vector_type(4)));
typedef float    f4  __attribute__((ext_vector_type(4)));
typedef float    fv16 __attribute__((ext_vector_type(16)));

typedef __attribute__((address_space(3))) unsigned int       lds_u32;
typedef const __attribute__((address_space(1))) unsigned int glob_u32;

// async global->LDS, 16B/lane; LDS dest = wave-uniform base + lane*16.
__device__ __forceinline__ void gld16(const void* g, void* l) {
    __builtin_amdgcn_global_load_lds((glob_u32*)g, (lds_u32*)l, 16, 0, 0);
}
__device__ __forceinline__ float exp2_hw(float x) { return __builtin_amdgcn_exp2f(x); }

#define QSCALE 0.18033688011112042f   // log2(e)/8

// ---------------- kernel 0a: w fp32 -> f16 (for attention l-sum) ----------
__global__ void wcvt_kernel(const float* __restrict__ w, _Float16* __restrict__ w16) {
    int i = blockIdx.x * 256 + threadIdx.x;
    if (i < B_ * S_) w16[i] = (_Float16)w[i];
}

// ---------------- kernel 0b: x fp32 -> f16 ----------------
__global__ void cvt_x_kernel(const float* __restrict__ x, _Float16* __restrict__ x16) {
    int i = (blockIdx.x * 256 + threadIdx.x) * 8;
    float4 u = *(const float4*)&x[i];
    float4 v = *(const float4*)&x[i + 4];
    h8 o;
    o[0] = (_Float16)u.x; o[1] = (_Float16)u.y; o[2] = (_Float16)u.z; o[3] = (_Float16)u.w;
    o[4] = (_Float16)v.x; o[5] = (_Float16)v.y; o[6] = (_Float16)v.z; o[7] = (_Float16)v.w;
    *(h8*)&x16[i] = o;
}

// ---------------- kernel 0c: W [K][N] fp32 -> Wt [N][K] f16 ----------------
__global__ __launch_bounds__(256) void transpose_w_kernel(
        const float* __restrict__ W, _Float16* __restrict__ Wt) {
    __shared__ float T[64][65];
    int k0 = blockIdx.x * 64, n0 = blockIdx.y * 64;
    int tid = threadIdx.x;
    int r = tid >> 4, c4 = (tid & 15) * 4;
#pragma unroll
    for (int i = 0; i < 4; i++) {
        int row = r + i * 16;
        float4 u = *(const float4*)&W[(size_t)(k0 + row) * N3_ + n0 + c4];
        T[c4 + 0][row] = u.x; T[c4 + 1][row] = u.y;
        T[c4 + 2][row] = u.z; T[c4 + 3][row] = u.w;
    }
    __syncthreads();
#pragma unroll
    for (int i = 0; i < 4; i++) {
        int rn = r + i * 16;
        h4 p;
        p[0] = (_Float16)T[rn][c4 + 0]; p[1] = (_Float16)T[rn][c4 + 1];
        p[2] = (_Float16)T[rn][c4 + 2]; p[3] = (_Float16)T[rn][c4 + 3];
        *(h4*)&Wt[(size_t)(n0 + rn) * E_ + k0 + c4] = p;
    }
}

// ---------------- kernel 1: QKV GEMM, 32x32x16 MFMA ----------------
// BM=128, BN=192 (one head: q|k|v), BK=64, 4 waves: wave = 64m x 96n.
// Q/K tiles use mfma(W,x) -> D[d][s] (d-contiguous packs -> [s][d] stores);
// V tiles use mfma(x,W) -> D[s][d], V' = (acc+bias)*w[s] -> Vt[d][s].
__global__ __launch_bounds__(256, 2) void qkv_gemm32(
        const _Float16* __restrict__ x16, const _Float16* __restrict__ wt,
        const float* __restrict__ bq, const float* __restrict__ w,
        _Float16* __restrict__ qws, _Float16* __restrict__ kws,
        _Float16* __restrict__ vtws) {
    __shared__ __align__(16) _Float16 As[128 * 64];   // 16 KB
    __shared__ __align__(16) _Float16 Ws[192 * 64];   // 24 KB

    int tid = threadIdx.x;
    int wid = tid >> 6, lane = tid & 63;
    int l31 = lane & 31, hi = lane >> 5;
    int wm = wid & 1, wn = wid >> 1;

    int L = blockIdx.x;
    int head = 2 * (L & 7) + (L >> 8);   // 2 heads per XCD
    int mb = (L >> 3) & 31;
    int m0 = mb * 128;
    int n0 = head * 192;
    int b = m0 >> 11;
    int bh = b * H_ + head;
    int sblk = m0 & 2047;

    int srow = lane >> 3;
    int schunk = (lane & 7) ^ srow;
    int l7 = l31 & 7;

    // bias folded into acc init
    fv16 acc[2][3];
#pragma unroll
    for (int ntl = 0; ntl < 3; ntl++) {
        int n_abs = wn * 96 + ntl * 32;
        int which = n_abs >> 6;
        fv16 ini;
        if (which == 2) {
            float bb = bq[n0 + n_abs + l31];
#pragma unroll
            for (int r = 0; r < 16; r++) ini[r] = bb;
        } else {
#pragma unroll
            for (int g = 0; g < 4; g++) {
                f4 bv = *(const f4*)&bq[n0 + n_abs + 8 * g + 4 * hi];
#pragma unroll
                for (int j = 0; j < 4; j++) ini[4 * g + j] = bv[j];
            }
        }
        acc[0][ntl] = ini; acc[1][ntl] = ini;
    }

    const _Float16* agp = &x16[(size_t)(m0 + wid * 32 + srow) * E_ + schunk * 8];
    const _Float16* wgp = &wt[(size_t)(n0 + wid * 48 + srow) * E_ + schunk * 8];

    for (int k0 = 0; k0 < E_; k0 += 64) {
#pragma unroll
        for (int j = 0; j < 4; j++)
            gld16(agp + (size_t)j * 8 * E_ + k0, &As[(wid * 32 + j * 8) * 64]);
#pragma unroll
        for (int j = 0; j < 6; j++)
            gld16(wgp + (size_t)j * 8 * E_ + k0, &Ws[(wid * 48 + j * 8) * 64]);
        __syncthreads();
#pragma unroll
        for (int step = 0; step < 4; step++) {
            int ph = ((2 * step + hi) ^ l7) * 8;
            h8 af[2], wf[3];
#pragma unroll
            for (int mt = 0; mt < 2; mt++)
                af[mt] = *(const h8*)&As[(wm * 64 + mt * 32 + l31) * 64 + ph];
#pragma unroll
            for (int ntl = 0; ntl < 3; ntl++)
                wf[ntl] = *(const h8*)&Ws[(wn * 96 + ntl * 32 + l31) * 64 + ph];
#pragma unroll
            for (int ntl = 0; ntl < 3; ntl++) {
                bool isv = (wn == 1) && (ntl >= 1);
#pragma unroll
                for (int mt = 0; mt < 2; mt++) {
                    if (isv)
                        acc[mt][ntl] = __builtin_amdgcn_mfma_f32_32x32x16_f16(af[mt], wf[ntl], acc[mt][ntl], 0, 0, 0);
                    else
                        acc[mt][ntl] = __builtin_amdgcn_mfma_f32_32x32x16_f16(wf[ntl], af[mt], acc[mt][ntl], 0, 0, 0);
                }
            }
        }
        __syncthreads();
    }

    // epilogue
#pragma unroll
    for (int ntl = 0; ntl < 3; ntl++) {
        int n_abs = wn * 96 + ntl * 32;
        int which = n_abs >> 6;
#pragma unroll
        for (int mt = 0; mt < 2; mt++) {
            if (which == 2) {
                // D rows = s, cols = d; V' = acc * w[s]; store Vt[d][s]
                int d = (n_abs & 63) + l31;
#pragma unroll
                for (int g = 0; g < 4; g++) {
                    int soff = wm * 64 + mt * 32 + 8 * g + 4 * hi;
                    f4 wf4 = *(const f4*)&w[m0 + soff];
                    h4 p;
#pragma unroll
                    for (int j = 0; j < 4; j++)
                        p[j] = (_Float16)(acc[mt][ntl][4 * g + j] * wf4[j]);
                    *(h4*)&vtws[((size_t)bh * 64 + d) * S_ + sblk + soff] = p;
                }
            } else {
                // D rows = d, cols = s; store [s][d]
                _Float16* dst = (which == 0) ? qws : kws;
                float scale = (which == 0) ? QSCALE : 1.0f;
                int s = sblk + wm * 64 + mt * 32 + l31;
#pragma unroll
                for (int g = 0; g < 4; g++) {
                    int d0 = (n_abs & 63) + 8 * g + 4 * hi;
                    h4 p;
#pragma unroll
                    for (int j = 0; j < 4; j++)
                        p[j] = (_Float16)(acc[mt][ntl][4 * g + j] * scale);
                    *(h4*)&dst[((size_t)bh * S_ + s) * 64 + d0] = p;
                }
            }
        }
    }
}

// ---------------- kernel 2: flash attention, 32x32 MFMA, no P round-trip --
// Wave = 32 q; block = 128 q; K-tile 64. S^T = K*QT (32x32x16), P stays in
// registers (C k-stripe == 32x32x8 B k-stripe), O^T = V'^T*P (32x32x8).
// q = lane&31 everywhere -> softmax state & epilogue lane-local.
__global__ __launch_bounds__(256, 2) void attn_kernel(
        const _Float16* __restrict__ q, const _Float16* __restrict__ k,
        const _Float16* __restrict__ vt, const _Float16* __restrict__ w16,
        float* __restrict__ out) {
    __shared__ __align__(16) _Float16 Ks[64 * 64];    // [kL][d]  8 KB
    __shared__ __align__(16) _Float16 Vts[64 * 64];   // [d][kL]  8 KB

    int tid = threadIdx.x;
    int wid = tid >> 6, lane = tid & 63;
    int l31 = lane & 31, hi = lane >> 5;
    int l7 = l31 & 7;
    int L = blockIdx.x;
    int bh = (L & 7) + 8 * (L >> 7);    // 16 q-tiles of a bh per XCD
    int qt = (L >> 3) & 15;
    int q0 = qt * 128;
    int b = bh >> 4, h = bh & 15;

    const _Float16* qbase = q + (size_t)bh * S_ * HD_;
    const _Float16* kbase = k + (size_t)bh * S_ * HD_;
    const _Float16* vbase = vt + (size_t)bh * HD_ * S_;
    const _Float16* wbase = w16 + (size_t)b * S_;

    int srow = lane >> 3;
    int schunk = (lane & 7) ^ srow;

    int qrow = q0 + wid * 32 + l31;
    h8 qf[4];
#pragma unroll
    for (int step = 0; step < 4; step++)
        qf[step] = *(const h8*)&qbase[(size_t)qrow * 64 + 16 * step + 8 * hi];

    fv16 o[2];
    o[0] = (fv16)0.0f; o[1] = (fv16)0.0f;
    float m_r = -INFINITY, l_r = 0.0f;

    const _Float16* kgp = &kbase[(size_t)(wid * 16 + srow) * 64 + schunk * 8];
    const _Float16* vgp = &vbase[(size_t)(wid * 16 + srow) * S_ + schunk * 8];

    for (int kt = 0; kt < 32; kt++) {
        int k0 = kt * 64;
#pragma unroll
        for (int j = 0; j < 2; j++) {
            gld16(kgp + (size_t)(k0 + j * 8) * 64, &Ks[(wid * 16 + j * 8) * 64]);
            gld16(vgp + (size_t)j * 8 * S_ + k0, &Vts[(wid * 16 + j * 8) * 64]);
        }
        // w f16 (global, L1-hot): lane's k = 32*kt2 + 8*g + 4*hi
        h4 wv[2][4];
#pragma unroll
        for (int kt2 = 0; kt2 < 2; kt2++)
#pragma unroll
            for (int g = 0; g < 4; g++)
                wv[kt2][g] = *(const h4*)&wbase[k0 + kt2 * 32 + 8 * g + 4 * hi];
        __syncthreads();

        // ---- S^T = K*Q^T : rows k, cols q=l31 ----
        fv16 st[2];
        st[0] = (fv16)0.0f; st[1] = (fv16)0.0f;
#pragma unroll
        for (int step = 0; step < 4; step++) {
            int ph = ((2 * step + hi) ^ l7) * 8;
#pragma unroll
            for (int kt2 = 0; kt2 < 2; kt2++) {
                h8 kf = *(const h8*)&Ks[(kt2 * 32 + l31) * 64 + ph];
                st[kt2] = __builtin_amdgcn_mfma_f32_32x32x16_f16(kf, qf[step], st[kt2], 0, 0, 0);
            }
        }

        // ---- online softmax (base 2), all state lane-local (q = l31) ----
        float rm = -INFINITY;
#pragma unroll
        for (int kt2 = 0; kt2 < 2; kt2++)
#pragma unroll
            for (int r = 0; r < 16; r++) rm = fmaxf(rm, st[kt2][r]);
        rm = fmaxf(rm, __shfl_xor(rm, 32));
        float mnew = fmaxf(m_r, rm);
        float rs = 0.0f;
        h4 pf[2][4];
#pragma unroll
        for (int kt2 = 0; kt2 < 2; kt2++)
#pragma unroll
            for (int g = 0; g < 4; g++) {
                f4 e;
#pragma unroll
                for (int j = 0; j < 4; j++) {
                    float ev = exp2_hw(st[kt2][4 * g + j] - mnew);
                    e[j] = ev;
                    rs += ev * (float)wv[kt2][g][j];
                }
                h4 p;
                p[0] = (_Float16)e[0]; p[1] = (_Float16)e[1];
                p[2] = (_Float16)e[2]; p[3] = (_Float16)e[3];
                pf[kt2][g] = p;
            }
        rs += __shfl_xor(rs, 32);
        float alpha = exp2_hw(m_r - mnew);
        m_r = mnew;
        l_r = l_r * alpha + rs;
        o[0] = o[0] * alpha;
        o[1] = o[1] * alpha;

        // ---- O^T += V'^T * P (32x32x8: B k-stripe matches C regs) ----
#pragma unroll
        for (int kt2 = 0; kt2 < 2; kt2++)
#pragma unroll
            for (int g = 0; g < 4; g++) {
                int ph = ((4 * kt2 + g) ^ l7) * 8 + hi * 4;
#pragma unroll
                for (int dt = 0; dt < 2; dt++) {
                    h4 vf = *(const h4*)&Vts[(dt * 32 + l31) * 64 + ph];
                    o[dt] = __builtin_amdgcn_mfma_f32_32x32x8f16(vf, pf[kt2][g], o[dt], 0, 0, 0);
                }
            }
        __syncthreads();
    }

    // ---- epilogue: O^T rows = d, cols = q (lane-local l) ----
    float linv = 1.0f / l_r;
    float* obase = &out[((size_t)(b * S_ + qrow)) * E_ + h * 64];
#pragma unroll
    for (int dt = 0; dt < 2; dt++)
#pragma unroll
        for (int g = 0; g < 4; g++) {
            int d0 = dt * 32 + 8 * g + 4 * hi;
            f4 ov;
#pragma unroll
            for (int j = 0; j < 4; j++) ov[j] = o[dt][4 * g + j] * linv;
            *(f4*)&obase[d0] = ov;
        }
}

extern "C" void kernel_launch(void* const* d_in, const int* in_sizes, int n_in,
                              void* d_out, int out_size, void* d_ws, size_t ws_size,
                              hipStream_t stream) {
    const float* x  = (const float*)d_in[0];
    const float* w  = (const float*)d_in[1];
    const float* Wq = (const float*)d_in[2];
    const float* bq = (const float*)d_in[3];
    float* out = (float*)d_out;

    char* p = (char*)d_ws;
    _Float16* x16 = (_Float16*)p;              p += (size_t)M_ * E_ * 2;
    _Float16* wt  = (_Float16*)p;              p += (size_t)E_ * N3_ * 2;
    _Float16* qb  = (_Float16*)p;              p += (size_t)M_ * E_ * 2;
    _Float16* kb  = (_Float16*)p;              p += (size_t)M_ * E_ * 2;
    _Float16* vtb = (_Float16*)p;              p += (size_t)M_ * E_ * 2;
    _Float16* w16 = (_Float16*)p;

    wcvt_kernel<<<dim3(16), dim3(256), 0, stream>>>(w, w16);
    cvt_x_kernel<<<dim3(M_ * E_ / 2048), dim3(256), 0, stream>>>(x, x16);
    transpose_w_kernel<<<dim3(E_ / 64, N3_ / 64), dim3(256), 0, stream>>>(Wq, wt);
    qkv_gemm32<<<dim3(512), dim3(256), 0, stream>>>(x16, wt, bq, w, qb, kb, vtb);
    attn_kernel<<<dim3(512), dim3(256), 0, stream>>>(qb, kb, vtb, w16, out);
}

// Round 6
// 179.500 us; speedup vs baseline: 5.2448x; 1.0387x over previous
//
#include <hip/hip_runtime.h>
#include <math.h>

#define B_  2
#define S_  2048
#define E_  1024
#define H_  16
#define HD_ 64
#define N3_ 3072
#define M_  (B_*S_)   // 4096

typedef _Float16 h8  __attribute__((ext_vector_type(8)));
typedef _Float16 h4  __attribute__((ext_vector_type(4)));
typedef float    f4  __attribute__((ext_vector_type(4)));
typedef float    fv16 __attribute__((ext_vector_type(16)));

typedef __attribute__((address_space(3))) unsigned int       lds_u32;
typedef const __attribute__((address_space(1))) unsigned int glob_u32;

// async global->LDS, 16B/lane; global addr per-lane, LDS dest = base + lane*16.
__device__ __forceinline__ void gld16(const void* g, void* l) {
    __builtin_amdgcn_global_load_lds((glob_u32*)g, (lds_u32*)l, 16, 0, 0);
}
__device__ __forceinline__ float exp2_hw(float x) { return __builtin_amdgcn_exp2f(x); }

#define QSCALE 0.18033688011112042f   // log2(e)/8

// ---------------- kernel 0b: x fp32 -> f16 ----------------
__global__ void cvt_x_kernel(const float* __restrict__ x, _Float16* __restrict__ x16) {
    int i = (blockIdx.x * 256 + threadIdx.x) * 8;
    float4 u = *(const float4*)&x[i];
    float4 v = *(const float4*)&x[i + 4];
    h8 o;
    o[0] = (_Float16)u.x; o[1] = (_Float16)u.y; o[2] = (_Float16)u.z; o[3] = (_Float16)u.w;
    o[4] = (_Float16)v.x; o[5] = (_Float16)v.y; o[6] = (_Float16)v.z; o[7] = (_Float16)v.w;
    *(h8*)&x16[i] = o;
}

// ---------------- kernel 0c: W [K][N] fp32 -> Wt [N][K] f16 ----------------
__global__ __launch_bounds__(256) void transpose_w_kernel(
        const float* __restrict__ W, _Float16* __restrict__ Wt) {
    __shared__ float T[64][65];
    int k0 = blockIdx.x * 64, n0 = blockIdx.y * 64;
    int tid = threadIdx.x;
    int r = tid >> 4, c4 = (tid & 15) * 4;
#pragma unroll
    for (int i = 0; i < 4; i++) {
        int row = r + i * 16;
        float4 u = *(const float4*)&W[(size_t)(k0 + row) * N3_ + n0 + c4];
        T[c4 + 0][row] = u.x; T[c4 + 1][row] = u.y;
        T[c4 + 2][row] = u.z; T[c4 + 3][row] = u.w;
    }
    __syncthreads();
#pragma unroll
    for (int i = 0; i < 4; i++) {
        int rn = r + i * 16;
        h4 p;
        p[0] = (_Float16)T[rn][c4 + 0]; p[1] = (_Float16)T[rn][c4 + 1];
        p[2] = (_Float16)T[rn][c4 + 2]; p[3] = (_Float16)T[rn][c4 + 3];
        *(h4*)&Wt[(size_t)(n0 + rn) * E_ + k0 + c4] = p;
    }
}

// ---------------- kernel 1: QKV GEMM, 32x32x16, 2-stage pipelined ----------
// BM=128, BN=192 (one head q|k|v), BK=64, wave = 64m x 96n.
// Swizzle: batch j stores chunk (lane&7)^(lane>>3)^(j&7); read c^(R&7)^((R>>3)&7).
__global__ __launch_bounds__(256, 2) void qkv_gemm32(
        const _Float16* __restrict__ x16, const _Float16* __restrict__ wt,
        const float* __restrict__ bq, const float* __restrict__ w,
        _Float16* __restrict__ qws, _Float16* __restrict__ kws,
        _Float16* __restrict__ vtws) {
    __shared__ __align__(16) _Float16 Ab[2][128 * 64];   // 32 KB
    __shared__ __align__(16) _Float16 Wb[2][192 * 64];   // 48 KB

    int tid = threadIdx.x;
    int wid = tid >> 6, lane = tid & 63;
    int l31 = lane & 31, hi = lane >> 5, l7 = l31 & 7;
    int srow = lane >> 3;
    int wm = wid & 1, wn = wid >> 1;

    int L = blockIdx.x;
    int head = 2 * (L & 7) + (L >> 8);   // 2 heads per XCD
    int mb = (L >> 3) & 31;
    int m0 = mb * 128;
    int n0 = head * 192;
    int b = m0 >> 11;
    int bh = b * H_ + head;
    int sblk = m0 & 2047;

    // bias folded into acc init
    fv16 acc[2][3];
#pragma unroll
    for (int ntl = 0; ntl < 3; ntl++) {
        int n_abs = wn * 96 + ntl * 32;
        int which = n_abs >> 6;
        fv16 ini;
        if (which == 2) {
            float bb = bq[n0 + n_abs + l31];
#pragma unroll
            for (int r = 0; r < 16; r++) ini[r] = bb;
        } else {
#pragma unroll
            for (int g = 0; g < 4; g++) {
                f4 bv = *(const f4*)&bq[n0 + n_abs + 8 * g + 4 * hi];
#pragma unroll
                for (int j = 0; j < 4; j++) ini[4 * g + j] = bv[j];
            }
        }
        acc[0][ntl] = ini; acc[1][ntl] = ini;
    }

    auto stage = [&](int t, int bf) {
        int k0 = t * 64;
#pragma unroll
        for (int j = 0; j < 4; j++) {
            int batch = wid * 4 + j;           // 0..15
            int row = batch * 8 + srow;
            int ch = (lane & 7) ^ srow ^ (batch & 7);
            gld16(&x16[(size_t)(m0 + row) * E_ + k0 + ch * 8], &Ab[bf][batch * 8 * 64]);
        }
#pragma unroll
        for (int j = 0; j < 6; j++) {
            int batch = wid * 6 + j;           // 0..23
            int row = batch * 8 + srow;
            int ch = (lane & 7) ^ srow ^ (batch & 7);
            gld16(&wt[(size_t)(n0 + row) * E_ + k0 + ch * 8], &Wb[bf][batch * 8 * 64]);
        }
    };

    stage(0, 0);

    for (int t = 0; t < 16; t++) {
        int bf = t & 1;
        __syncthreads();                  // drains DMA of tile t, fences buffers
        if (t < 15) stage(t + 1, bf ^ 1); // prefetch overlaps compute below
#pragma unroll
        for (int step = 0; step < 4; step++) {
            h8 af[2], wf[3];
#pragma unroll
            for (int mt = 0; mt < 2; mt++) {
                int R = wm * 64 + mt * 32 + l31;
                int ph = ((2 * step + hi) ^ l7 ^ ((mt * 4 + (l31 >> 3)) & 7)) * 8;
                af[mt] = *(const h8*)&Ab[bf][R * 64 + ph];
            }
#pragma unroll
            for (int ntl = 0; ntl < 3; ntl++) {
                int R = wn * 96 + ntl * 32 + l31;
                int ph = ((2 * step + hi) ^ l7 ^ ((wn * 12 + ntl * 4 + (l31 >> 3)) & 7)) * 8;
                wf[ntl] = *(const h8*)&Wb[bf][R * 64 + ph];
            }
#pragma unroll
            for (int ntl = 0; ntl < 3; ntl++) {
                bool isv = (wn == 1) && (ntl >= 1);
#pragma unroll
                for (int mt = 0; mt < 2; mt++) {
                    if (isv)
                        acc[mt][ntl] = __builtin_amdgcn_mfma_f32_32x32x16_f16(af[mt], wf[ntl], acc[mt][ntl], 0, 0, 0);
                    else
                        acc[mt][ntl] = __builtin_amdgcn_mfma_f32_32x32x16_f16(wf[ntl], af[mt], acc[mt][ntl], 0, 0, 0);
                }
            }
        }
    }

    // epilogue
#pragma unroll
    for (int ntl = 0; ntl < 3; ntl++) {
        int n_abs = wn * 96 + ntl * 32;
        int which = n_abs >> 6;
#pragma unroll
        for (int mt = 0; mt < 2; mt++) {
            if (which == 2) {
                // D rows = s, cols = d; V' = acc * w[s]; store Vt[d][s]
                int d = (n_abs & 63) + l31;
#pragma unroll
                for (int g = 0; g < 4; g++) {
                    int soff = wm * 64 + mt * 32 + 8 * g + 4 * hi;
                    f4 wf4 = *(const f4*)&w[m0 + soff];
                    h4 p;
#pragma unroll
                    for (int j = 0; j < 4; j++)
                        p[j] = (_Float16)(acc[mt][ntl][4 * g + j] * wf4[j]);
                    *(h4*)&vtws[((size_t)bh * 64 + d) * S_ + sblk + soff] = p;
                }
            } else {
                // D rows = d, cols = s; store [s][d]
                _Float16* dst = (which == 0) ? qws : kws;
                float scale = (which == 0) ? QSCALE : 1.0f;
                int s = sblk + wm * 64 + mt * 32 + l31;
#pragma unroll
                for (int g = 0; g < 4; g++) {
                    int d0 = (n_abs & 63) + 8 * g + 4 * hi;
                    h4 p;
#pragma unroll
                    for (int j = 0; j < 4; j++)
                        p[j] = (_Float16)(acc[mt][ntl][4 * g + j] * scale);
                    *(h4*)&dst[((size_t)bh * S_ + s) * 64 + d0] = p;
                }
            }
        }
    }
}

// ---------------- kernel 2: flash attention, pipelined, no P round-trip ----
// Wave = 32 q, block = 128 q, K-tile 64, 2-stage double-buffered staging.
// S^T = K*Q^T (32x32x16); P in regs (C k-stripe == 32x32x8 B k-stripe);
// O^T = V'^T*P (32x32x8). q = lane&31 -> softmax state lane-local.
__global__ __launch_bounds__(256, 2) void attn_kernel(
        const _Float16* __restrict__ q, const _Float16* __restrict__ k,
        const _Float16* __restrict__ vt, const float* __restrict__ w,
        float* __restrict__ out) {
    __shared__ __align__(16) _Float16 Kb[2][64 * 64];   // 16 KB
    __shared__ __align__(16) _Float16 Vb[2][64 * 64];   // 16 KB
    __shared__ __align__(16) float lws[2048];           //  8 KB: w row (fp32)

    int tid = threadIdx.x;
    int wid = tid >> 6, lane = tid & 63;
    int l31 = lane & 31, hi = lane >> 5, l7 = l31 & 7;
    int srow = lane >> 3;
    int L = blockIdx.x;
    int bh = (L & 7) + 8 * (L >> 7);    // 16 q-tiles of a bh per XCD
    int qt = (L >> 3) & 15;
    int q0 = qt * 128;
    int b = bh >> 4, h = bh & 15;

    const _Float16* qbase = q + (size_t)bh * S_ * HD_;
    const _Float16* kbase = k + (size_t)bh * S_ * HD_;
    const _Float16* vbase = vt + (size_t)bh * HD_ * S_;
    const float* wbase = w + (size_t)b * S_;

    // stage w row (fp32, 8 KB, 8 batches of 1 KB; 2 per wave, no swizzle)
#pragma unroll
    for (int j = 0; j < 2; j++) {
        int batch = wid + 4 * j;
        gld16(&wbase[batch * 256 + lane * 4], &lws[batch * 256]);
    }

    auto stage = [&](int kt, int bf) {
        int k0 = kt * 64;
#pragma unroll
        for (int j = 0; j < 2; j++) {
            int batch = wid * 2 + j;           // 0..7
            int row = batch * 8 + srow;
            int ch = (lane & 7) ^ srow ^ (batch & 7);
            gld16(&kbase[(size_t)(k0 + row) * 64 + ch * 8], &Kb[bf][batch * 8 * 64]);
            gld16(&vbase[(size_t)row * S_ + k0 + ch * 8], &Vb[bf][batch * 8 * 64]);
        }
    };

    stage(0, 0);

    int qrow = q0 + wid * 32 + l31;
    h8 qf[4];
#pragma unroll
    for (int step = 0; step < 4; step++)
        qf[step] = *(const h8*)&qbase[(size_t)qrow * 64 + 16 * step + 8 * hi];

    fv16 o[2];
    o[0] = (fv16)0.0f; o[1] = (fv16)0.0f;
    float m_r = -INFINITY, l_r = 0.0f;

    for (int kt = 0; kt < 32; kt++) {
        int bf = kt & 1;
        __syncthreads();                    // drains DMA of tile kt
        if (kt < 31) stage(kt + 1, bf ^ 1); // overlaps compute below

        // ---- S^T = K*Q^T : rows k, cols q=l31 ----
        fv16 st[2];
        st[0] = (fv16)0.0f; st[1] = (fv16)0.0f;
#pragma unroll
        for (int step = 0; step < 4; step++) {
#pragma unroll
            for (int kt2 = 0; kt2 < 2; kt2++) {
                int R = kt2 * 32 + l31;
                int ph = ((2 * step + hi) ^ l7 ^ ((kt2 * 4 + (l31 >> 3)) & 7)) * 8;
                h8 kf = *(const h8*)&Kb[bf][R * 64 + ph];
                st[kt2] = __builtin_amdgcn_mfma_f32_32x32x16_f16(kf, qf[step], st[kt2], 0, 0, 0);
            }
        }

        // ---- online softmax (base 2), lane-local state (q = l31) ----
        float rm = -INFINITY;
#pragma unroll
        for (int kt2 = 0; kt2 < 2; kt2++)
#pragma unroll
            for (int r = 0; r < 16; r++) rm = fmaxf(rm, st[kt2][r]);
        rm = fmaxf(rm, __shfl_xor(rm, 32));
        float mnew = fmaxf(m_r, rm);
        float rs = 0.0f;
        h4 pf[2][4];
        int k0 = kt * 64;
#pragma unroll
        for (int kt2 = 0; kt2 < 2; kt2++)
#pragma unroll
            for (int g = 0; g < 4; g++) {
                f4 wv = *(const f4*)&lws[k0 + kt2 * 32 + 8 * g + 4 * hi];
                f4 e;
#pragma unroll
                for (int j = 0; j < 4; j++) {
                    float ev = exp2_hw(st[kt2][4 * g + j] - mnew);
                    e[j] = ev;
                    rs += ev * wv[j];
                }
                h4 p;
                p[0] = (_Float16)e[0]; p[1] = (_Float16)e[1];
                p[2] = (_Float16)e[2]; p[3] = (_Float16)e[3];
                pf[kt2][g] = p;
            }
        rs += __shfl_xor(rs, 32);
        float alpha = exp2_hw(m_r - mnew);
        m_r = mnew;
        l_r = l_r * alpha + rs;
        o[0] = o[0] * alpha;
        o[1] = o[1] * alpha;

        // ---- O^T += V'^T * P (32x32x8: B k-stripe matches C regs) ----
#pragma unroll
        for (int kt2 = 0; kt2 < 2; kt2++)
#pragma unroll
            for (int g = 0; g < 4; g++) {
                int c = 4 * kt2 + g;
#pragma unroll
                for (int dt = 0; dt < 2; dt++) {
                    int R = dt * 32 + l31;
                    int ph = (c ^ l7 ^ ((dt * 4 + (l31 >> 3)) & 7)) * 8 + hi * 4;
                    h4 vf = *(const h4*)&Vb[bf][R * 64 + ph];
                    o[dt] = __builtin_amdgcn_mfma_f32_32x32x8f16(vf, pf[kt2][g], o[dt], 0, 0, 0);
                }
            }
    }

    // ---- epilogue: O^T rows = d, cols = q (lane-local l) ----
    float linv = 1.0f / l_r;
    float* obase = &out[((size_t)(b * S_ + qrow)) * E_ + h * 64];
#pragma unroll
    for (int dt = 0; dt < 2; dt++)
#pragma unroll
        for (int g = 0; g < 4; g++) {
            int d0 = dt * 32 + 8 * g + 4 * hi;
            f4 ov;
#pragma unroll
            for (int j = 0; j < 4; j++) ov[j] = o[dt][4 * g + j] * linv;
            *(f4*)&obase[d0] = ov;
        }
}

extern "C" void kernel_launch(void* const* d_in, const int* in_sizes, int n_in,
                              void* d_out, int out_size, void* d_ws, size_t ws_size,
                              hipStream_t stream) {
    const float* x  = (const float*)d_in[0];
    const float* w  = (const float*)d_in[1];
    const float* Wq = (const float*)d_in[2];
    const float* bq = (const float*)d_in[3];
    float* out = (float*)d_out;

    char* p = (char*)d_ws;
    _Float16* x16 = (_Float16*)p;              p += (size_t)M_ * E_ * 2;
    _Float16* wt  = (_Float16*)p;              p += (size_t)E_ * N3_ * 2;
    _Float16* qb  = (_Float16*)p;              p += (size_t)M_ * E_ * 2;
    _Float16* kb  = (_Float16*)p;              p += (size_t)M_ * E_ * 2;
    _Float16* vtb = (_Float16*)p;

    cvt_x_kernel<<<dim3(M_ * E_ / 2048), dim3(256), 0, stream>>>(x, x16);
    transpose_w_kernel<<<dim3(E_ / 64, N3_ / 64), dim3(256), 0, stream>>>(Wq, wt);
    qkv_gemm32<<<dim3(512), dim3(256), 0, stream>>>(x16, wt, bq, w, qb, kb, vtb);
    attn_kernel<<<dim3(512), dim3(256), 0, stream>>>(qb, kb, vtb, w, out);
}